// Round 1
// baseline (11.066 us; speedup 1.0000x reference)
//
#include <hip/hip_runtime.h>
#include <hip/hip_bf16.h>

// Problem constants (from reference): B=8, N=4096, D=256, K=2048.
// Output = merged[:, :K] = ru = gather(r, idx_unbiased) — everything else in
// the reference is dead code (concat puts ru first, slice takes exactly K rows).
//
// Pure gather: out[b,i,:] = r[b, idx_unbiased[b,i], :]. f32, D=256 -> 64
// float4 per row; consecutive threads read consecutive float4 within a row
// (coalesced, rows are 1 KB contiguous).

namespace {
constexpr int B = 8;
constexpr int N = 4096;
constexpr int D = 256;
constexpr int K = 2048;
constexpr int V = D / 4;            // float4 per row = 64
constexpr long TOTAL = (long)B * K * V;  // 1,048,576 float4 elements
}

__global__ void __launch_bounds__(256) gather_ru_kernel(
    const float4* __restrict__ r,      // (B, N, D) viewed as float4: (B*N*V)
    const int* __restrict__ idx,       // (B, K)
    float4* __restrict__ out)          // (B, K, D) viewed as float4
{
    for (long t = (long)blockIdx.x * blockDim.x + threadIdx.x; t < TOTAL;
         t += (long)gridDim.x * blockDim.x) {
        const int dvec = (int)(t & (V - 1));    // which float4 within the row
        const int row  = (int)(t >> 6);         // b*K + i
        const int b    = row >> 11;             // row / K
        const int src  = idx[row];              // idx_unbiased[b][i]
        out[t] = r[((long)b * N + src) * V + dvec];
    }
}

extern "C" void kernel_launch(void* const* d_in, const int* in_sizes, int n_in,
                              void* d_out, int out_size, void* d_ws, size_t ws_size,
                              hipStream_t stream) {
    // setup_inputs order: r(0), e(1), idx_unbiased(2), idx_biased(3),
    //                     Wc1_w(4), Wc1_b(5), Wc2_w(6), Wc2_b(7)
    const float4* r  = (const float4*)d_in[0];
    const int* idx_u = (const int*)d_in[2];
    float4* out      = (float4*)d_out;

    const int block = 256;
    const int grid  = 2048;  // grid-stride, 2 float4 per thread
    gather_ru_kernel<<<grid, block, 0, stream>>>(r, idx_u, out);
}